// Round 10
// baseline (113.742 us; speedup 1.0000x reference)
//
#include <hip/hip_runtime.h>

typedef __bf16 bf16_t;
typedef bf16_t bf16x8 __attribute__((ext_vector_type(8)));
typedef bf16_t bf16x4 __attribute__((ext_vector_type(4)));
typedef float f32x4 __attribute__((ext_vector_type(4)));

#define SEQLEN 2048
#define EMB 1024
#define NHEADS 16
#define N3 3072
#define NBATCH 2
#define NEG_INF (-__builtin_inff())
#define SC2 0.18033688011112042f   // 0.125 * log2(e): softmax in exp2 domain

// async global->LDS, 16B per lane. LDS base must be wave-uniform.
__device__ __forceinline__ void async16(bf16_t* lds, const bf16_t* g) {
    __builtin_amdgcn_global_load_lds(
        (const __attribute__((address_space(1))) void*)g,
        (__attribute__((address_space(3))) void*)lds, 16, 0, 0);
}

// ---------------------------------------------------------------------------
// Combined weight transpose + fp32->bf16: W_qkv (48 col-blocks, Q cols
// pre-scaled by SC2) and W_out (16 col-blocks) in one launch.
// ---------------------------------------------------------------------------
__global__ __launch_bounds__(256) void transpose_weights(
    const float* __restrict__ Wqkv, const float* __restrict__ Wout,
    bf16_t* __restrict__ Wqkv_t, bf16_t* __restrict__ Wout_t)
{
    __shared__ float tile[64][65];
    int bx = blockIdx.x;
    const int k0 = blockIdx.y * 64;
    const float* W; bf16_t* Wt; int N; float s;
    if (bx < 48) { W = Wqkv; Wt = Wqkv_t; N = N3;  s = (bx * 64 < EMB) ? SC2 : 1.0f; }
    else         { bx -= 48; W = Wout; Wt = Wout_t; N = EMB; s = 1.0f; }
    const int n0 = bx * 64;
    const int t = threadIdx.x;
    const int nl = t & 63, k4 = t >> 6;
#pragma unroll
    for (int i = 0; i < 16; ++i) {
        int kk = k4 + i * 4;
        tile[kk][nl] = W[(size_t)(k0 + kk) * N + n0 + nl];
    }
    __syncthreads();
    const int kl = t & 63, n4 = t >> 6;
#pragma unroll
    for (int i = 0; i < 16; ++i) {
        int nn = n4 + i * 4;
        Wt[(size_t)(n0 + nn) * EMB + k0 + kl] = (bf16_t)(tile[kl][nn] * s);
    }
}

// ---------------------------------------------------------------------------
// fp32 -> bf16 convert (X pre-convert), 8 elems/thread
// ---------------------------------------------------------------------------
__global__ __launch_bounds__(256) void cvt_f32_bf16(
    const float* __restrict__ in, bf16_t* __restrict__ out, int n)
{
    const int i = (blockIdx.x * 256 + threadIdx.x) * 8;
    if (i >= n) return;
    float4 a = *(const float4*)&in[i];
    float4 b = *(const float4*)&in[i + 4];
    bf16_t v[8];
    v[0] = (bf16_t)a.x; v[1] = (bf16_t)a.y; v[2] = (bf16_t)a.z; v[3] = (bf16_t)a.w;
    v[4] = (bf16_t)b.x; v[5] = (bf16_t)b.y; v[6] = (bf16_t)b.z; v[7] = (bf16_t)b.w;
    *(float4*)&out[i] = *(float4*)&v[0];
}

// ---------------------------------------------------------------------------
// GEMM 128x128, BK=64, T2-swizzled (round-9 verbatim, verified).
// ---------------------------------------------------------------------------
template<bool OUT_BF16, bool V_SPLIT>
__global__ __launch_bounds__(256) void gemm_bt_kernel(
    const bf16_t* __restrict__ A, const bf16_t* __restrict__ Bt,
    const float* __restrict__ bias, void* __restrict__ Cp,
    bf16_t* __restrict__ vt, int scale_q,
    int Mdim, int Ndim, int Kdim)
{
    __shared__ bf16_t As[128 * 64];   // 16 KB
    __shared__ bf16_t Bs[128 * 64];   // 16 KB
    const int nb = Ndim >> 7;
    const int cpx = gridDim.x >> 3;
    const int bid = (blockIdx.x & 7) * cpx + (blockIdx.x >> 3);
    const int bx = bid % nb, by = bid / nb;
    const int r0 = by << 7, c0 = bx << 7;
    const int t = threadIdx.x, lane = t & 63;
    const int wid = t >> 6;
    const int wm = wid >> 1, wn = wid & 1;
    const int lr = lane & 15, lg = lane >> 4;

    const int glrow = wid * 32 + (lane >> 3);
    const int gsw = ((lane & 7) ^ (lane >> 3)) << 3;     // elems
    const bf16_t* gA = &A[(size_t)(r0 + glrow) * Kdim + gsw];
    const bf16_t* gB = &Bt[(size_t)(c0 + glrow) * Kdim + gsw];
    bf16_t* ldsA = &As[wid * 2048];
    bf16_t* ldsB = &Bs[wid * 2048];
    const size_t row8 = (size_t)8 * Kdim;

    const int fragb0 = (lr * 128 + lg * 16) ^ ((lr & 7) << 4);
    const int fragb1 = (lr * 128 + 64 + lg * 16) ^ ((lr & 7) << 4);

    f32x4 acc[4][4] = {};
    const int KT = Kdim >> 6;
    for (int kt = 0; kt < KT; ++kt) {
        const bf16_t* a = gA + kt * 64;
        const bf16_t* b = gB + kt * 64;
        async16(ldsA,        a);
        async16(ldsA + 512,  a + row8);
        async16(ldsA + 1024, a + 2 * row8);
        async16(ldsA + 1536, a + 3 * row8);
        async16(ldsB,        b);
        async16(ldsB + 512,  b + row8);
        async16(ldsB + 1024, b + 2 * row8);
        async16(ldsB + 1536, b + 3 * row8);
        __syncthreads();

        const char* Ab = (const char*)As + wm * 8192;
        const char* Bb = (const char*)Bs + wn * 8192;
        bf16x8 af[4], bfm[4];
#pragma unroll
        for (int m = 0; m < 4; ++m)
            af[m] = *(const bf16x8*)(Ab + m * 2048 + fragb0);
#pragma unroll
        for (int n = 0; n < 4; ++n)
            bfm[n] = *(const bf16x8*)(Bb + n * 2048 + fragb0);
#pragma unroll
        for (int m = 0; m < 4; ++m)
#pragma unroll
            for (int n = 0; n < 4; ++n)
                acc[m][n] = __builtin_amdgcn_mfma_f32_16x16x32_bf16(
                    af[m], bfm[n], acc[m][n], 0, 0, 0);
#pragma unroll
        for (int m = 0; m < 4; ++m)
            af[m] = *(const bf16x8*)(Ab + m * 2048 + fragb1);
#pragma unroll
        for (int n = 0; n < 4; ++n)
            bfm[n] = *(const bf16x8*)(Bb + n * 2048 + fragb1);
#pragma unroll
        for (int m = 0; m < 4; ++m)
#pragma unroll
            for (int n = 0; n < 4; ++n)
                acc[m][n] = __builtin_amdgcn_mfma_f32_16x16x32_bf16(
                    af[m], bfm[n], acc[m][n], 0, 0, 0);
        __syncthreads();
    }

    const bool vmode = V_SPLIT && (c0 >= 2 * EMB);
#pragma unroll
    for (int m = 0; m < 4; ++m) {
#pragma unroll
        for (int n = 0; n < 4; ++n) {
            const int col = c0 + wn * 64 + n * 16 + lr;
            float bval = bias[col];
            if (scale_q && col < EMB) bval *= SC2;
            if (vmode) {
                const int h = (col - 2 * EMB) >> 6, dd = col & 63;
                const int bb = r0 >> 11;
                const int sbase = (r0 & (SEQLEN - 1)) + wm * 64 + m * 16 + lg * 4;
                bf16x4 pk;
#pragma unroll
                for (int j = 0; j < 4; ++j) pk[j] = (bf16_t)(acc[m][n][j] + bval);
                *(bf16x4*)&vt[(size_t)((bb * 16 + h) * 64 + dd) * SEQLEN + sbase] = pk;
            } else {
#pragma unroll
                for (int j = 0; j < 4; ++j) {
                    const int row = r0 + wm * 64 + m * 16 + lg * 4 + j;
                    const float v = acc[m][n][j] + bval;
                    if (OUT_BF16)
                        ((bf16_t*)Cp)[(size_t)row * Ndim + col] = (bf16_t)v;
                    else
                        ((float*)Cp)[(size_t)row * Ndim + col] = v;
                }
            }
        }
    }
}

// ---------------------------------------------------------------------------
// Causal flash attention v6: QBLK=128, TWO q-sets per wave (32 q-rows/wave).
// The same 16 K/V LDS fragment reads feed both sets' MFMAs -> LDS read
// traffic per unit work HALVES vs v5. Per-set online softmax state;
// per-set wave-uniform mask trigger kt*64+63 > qbase_s.
// Grid: 512 blocks = 32 bh x 16 q-tiles; dispatch pairs u <-> 15-u.
// ---------------------------------------------------------------------------
__global__ __launch_bounds__(256, 2) void attn_kernel(
    const bf16_t* __restrict__ qkv, const bf16_t* __restrict__ vt,
    bf16_t* __restrict__ attn_out)
{
    __shared__ bf16_t Kl[2][4096];
    __shared__ bf16_t Vl[2][4096];
    const int d = blockIdx.x;
    const int r = d >> 8;                 // 2 rounds of 256
    const int idx = d & 255;
    const int bh = idx & 31;              // bh & 7 == XCD slot -> 4 KV streams/XCD
    const int u = idx >> 5;               // 0..7
    const int qt = r ? (15 - u) : u;      // paired: steps sum = 34 per CU pair
    const int b = bh >> 4, h = bh & 15;
    const int q0 = qt << 7;
    const int ktend = 2 * qt + 1;         // inclusive last 64-wide k-tile
    const int t = threadIdx.x, lane = t & 63, wid = t >> 6;
    const int lr = lane & 15, lg = lane >> 4;
    const int sr = t >> 2, sc16 = (t & 3) << 4;

    const int fragb0 = (lr * 128 + lg * 16) ^ ((lr & 7) << 4);
    const int fragb1 = (lr * 128 + 64 + lg * 16) ^ ((lr & 7) << 4);
    const int stb0   = (sr * 128 + sc16 * 2) ^ ((sr & 7) << 4);
    const int stb1   = (sr * 128 + sc16 * 2 + 16) ^ ((sr & 7) << 4);

    const bf16_t* kp = &qkv[(size_t)(b * SEQLEN + sr) * N3 + EMB + h * 64 + sc16];
    const bf16_t* vp = &vt[(size_t)(bh * 64 + sr) * SEQLEN + sc16];
    const size_t kstep = (size_t)64 * N3;

    const int qb0 = q0 + wid * 32;        // set0 q-base (wave-uniform)
    const int qb1 = qb0 + 16;             // set1 q-base
    const int qg0 = qb0 + lr, qg1 = qb1 + lr;
    bf16x8 qa0, qa1, qa2, qa3;
    {
        const bf16_t* q0p = &qkv[(size_t)(b * SEQLEN + qg0) * N3 + h * 64];
        const bf16_t* q1p = &qkv[(size_t)(b * SEQLEN + qg1) * N3 + h * 64];
        qa0 = *(const bf16x8*)&q0p[lg * 8];
        qa1 = *(const bf16x8*)&q0p[32 + lg * 8];
        qa2 = *(const bf16x8*)&q1p[lg * 8];
        qa3 = *(const bf16x8*)&q1p[32 + lg * 8];
    }
    bf16x8 ones;
#pragma unroll
    for (int i = 0; i < 8; ++i) ones[i] = (bf16_t)1.0f;

    f32x4 o0[4] = {}, o1[4] = {};
    f32x4 ol0 = {}, ol1 = {};
    float m0 = NEG_INF, m1 = NEG_INF;

    auto stK = [&](char* base, float4 a, float4 c) {
        *(float4*)(base + stb0) = a; *(float4*)(base + stb1) = c;
    };
    auto stV = [&](char* base, float4 a, float4 c) {
        float4 w0 = {a.x, a.y, c.x, c.y};
        float4 w1 = {a.z, a.w, c.z, c.w};
        *(float4*)(base + stb0) = w0; *(float4*)(base + stb1) = w1;
    };

    {
        float4 k0 = *(const float4*)kp, k1 = *(const float4*)(kp + 8);
        float4 v0 = *(const float4*)vp, v1 = *(const float4*)(vp + 8);
        stK((char*)Kl[0], k0, k1);
        stV((char*)Vl[0], v0, v1);
    }
    __syncthreads();
    int cur = 0;
    for (int kt = 0; kt <= ktend; ++kt) {
        float4 nk0, nk1, nv0, nv1;
        const bool more = (kt < ktend);
        if (more) {
            kp += kstep; vp += 64;
            nk0 = *(const float4*)kp; nk1 = *(const float4*)(kp + 8);
            nv0 = *(const float4*)vp; nv1 = *(const float4*)(vp + 8);
        }

        const char* Kc = (const char*)Kl[cur];
        const char* Vc = (const char*)Vl[cur];

        // QK^T both sets share the K fragments
        f32x4 s0[4] = {}, s1[4] = {};
        __builtin_amdgcn_s_setprio(1);
#pragma unroll
        for (int n = 0; n < 4; ++n) {
            bf16x8 kb0 = *(const bf16x8*)(Kc + (fragb0 + n * 2048));
            bf16x8 kb1 = *(const bf16x8*)(Kc + (fragb1 + n * 2048));
            s0[n] = __builtin_amdgcn_mfma_f32_16x16x32_bf16(kb0, qa0, s0[n], 0, 0, 0);
            s0[n] = __builtin_amdgcn_mfma_f32_16x16x32_bf16(kb1, qa1, s0[n], 0, 0, 0);
            s1[n] = __builtin_amdgcn_mfma_f32_16x16x32_bf16(kb0, qa2, s1[n], 0, 0, 0);
            s1[n] = __builtin_amdgcn_mfma_f32_16x16x32_bf16(kb1, qa3, s1[n], 0, 0, 0);
        }
        __builtin_amdgcn_s_setprio(0);

        // causal mask, per set (wave-uniform trigger)
        const int kbase = kt << 6;
        if (kbase + 63 > qb0) {
#pragma unroll
            for (int n = 0; n < 4; ++n)
#pragma unroll
                for (int j = 0; j < 4; ++j) {
                    const int kg = kbase + n * 16 + lg * 4 + j;
                    s0[n][j] = (kg <= qg0) ? s0[n][j] : NEG_INF;
                }
        }
        if (kbase + 63 > qb1) {
#pragma unroll
            for (int n = 0; n < 4; ++n)
#pragma unroll
                for (int j = 0; j < 4; ++j) {
                    const int kg = kbase + n * 16 + lg * 4 + j;
                    s1[n][j] = (kg <= qg1) ? s1[n][j] : NEG_INF;
                }
        }

        // per-lane maxes
        float pm0 = NEG_INF, pm1 = NEG_INF;
#pragma unroll
        for (int n = 0; n < 4; ++n) {
            pm0 = fmaxf(pm0, fmaxf(fmaxf(s0[n][0], s0[n][1]), fmaxf(s0[n][2], s0[n][3])));
            pm1 = fmaxf(pm1, fmaxf(fmaxf(s1[n][0], s1[n][1]), fmaxf(s1[n][2], s1[n][3])));
        }

        // T13 defer-rescale (joint trigger, per-set update)
        if (__any((pm0 > m0 + 8.f) || (pm1 > m1 + 8.f))) {
            float pa = fmaxf(pm0, __shfl_xor(pm0, 16));
            pa = fmaxf(pa, __shfl_xor(pa, 32));
            float pb = fmaxf(pm1, __shfl_xor(pm1, 16));
            pb = fmaxf(pb, __shfl_xor(pb, 32));
            const float mn0 = fmaxf(m0, pa);
            const float mn1 = fmaxf(m1, pb);
            const float a0 = exp2f(m0 - mn0);
            const float a1 = exp2f(m1 - mn1);
            m0 = mn0; m1 = mn1;
            float al0[4], al1[4];
#pragma unroll
            for (int j = 0; j < 4; ++j) {
                al0[j] = __shfl(a0, lg * 4 + j);
                al1[j] = __shfl(a1, lg * 4 + j);
            }
#pragma unroll
            for (int dn = 0; dn < 4; ++dn)
#pragma unroll
                for (int j = 0; j < 4; ++j) {
                    o0[dn][j] *= al0[j];
                    o1[dn][j] *= al1[j];
                }
#pragma unroll
            for (int j = 0; j < 4; ++j) { ol0[j] *= al0[j]; ol1[j] *= al1[j]; }
        }

        // exp2 per set
#pragma unroll
        for (int n = 0; n < 4; ++n)
#pragma unroll
            for (int j = 0; j < 4; ++j) {
                s0[n][j] = exp2f(s0[n][j] - m0);
                s1[n][j] = exp2f(s1[n][j] - m1);
            }

        // T12: P -> bf16 + permlane32_swap, per set
        union UW { unsigned w[4]; bf16x8 v; };
        bf16x8 pa0s0, pa1s0, pa0s1, pa1s1;
        {
            unsigned pk00, pk01, pk10, pk11, pk20, pk21, pk30, pk31;
            asm("v_cvt_pk_bf16_f32 %0, %1, %2" : "=v"(pk00) : "v"(s0[0][0]), "v"(s0[0][1]));
            asm("v_cvt_pk_bf16_f32 %0, %1, %2" : "=v"(pk01) : "v"(s0[0][2]), "v"(s0[0][3]));
            asm("v_cvt_pk_bf16_f32 %0, %1, %2" : "=v"(pk10) : "v"(s0[1][0]), "v"(s0[1][1]));
            asm("v_cvt_pk_bf16_f32 %0, %1, %2" : "=v"(pk11) : "v"(s0[1][2]), "v"(s0[1][3]));
            asm("v_cvt_pk_bf16_f32 %0, %1, %2" : "=v"(pk20) : "v"(s0[2][0]), "v"(s0[2][1]));
            asm("v_cvt_pk_bf16_f32 %0, %1, %2" : "=v"(pk21) : "v"(s0[2][2]), "v"(s0[2][3]));
            asm("v_cvt_pk_bf16_f32 %0, %1, %2" : "=v"(pk30) : "v"(s0[3][0]), "v"(s0[3][1]));
            asm("v_cvt_pk_bf16_f32 %0, %1, %2" : "=v"(pk31) : "v"(s0[3][2]), "v"(s0[3][3]));
            asm("v_permlane32_swap_b32 %0, %1" : "+v"(pk00), "+v"(pk10));
            asm("v_permlane32_swap_b32 %0, %1" : "+v"(pk01), "+v"(pk11));
            asm("v_permlane32_swap_b32 %0, %1" : "+v"(pk20), "+v"(pk30));
            asm("v_permlane32_swap_b32 %0, %1" : "+v"(pk21), "+v"(pk31));
            UW ua, ub;
            ua.w[0] = pk00; ua.w[1] = pk01; ua.w[2] = pk10; ua.w[3] = pk11;
            ub.w[0] = pk20; ub.w[1] = pk21; ub.w[2] = pk30; ub.w[3] = pk31;
            pa0s0 = ua.v; pa1s0 = ub.v;
        }
        {
            unsigned pk00, pk01, pk10, pk11, pk20, pk21, pk30, pk31;
            asm("v_cvt_pk_bf16_f32 %0, %1, %2" : "=v"(pk00) : "v"(s1[0][0]), "v"(s1[0][1]));
            asm("v_cvt_pk_bf16_f32 %0, %1, %2" : "=v"(pk01) : "v"(s1[0][2]), "v"(s1[0][3]));
            asm("v_cvt_pk_bf16_f32 %0, %1, %2" : "=v"(pk10) : "v"(s1[1][0]), "v"(s1[1][1]));
            asm("v_cvt_pk_bf16_f32 %0, %1, %2" : "=v"(pk11) : "v"(s1[1][2]), "v"(s1[1][3]));
            asm("v_cvt_pk_bf16_f32 %0, %1, %2" : "=v"(pk20) : "v"(s1[2][0]), "v"(s1[2][1]));
            asm("v_cvt_pk_bf16_f32 %0, %1, %2" : "=v"(pk21) : "v"(s1[2][2]), "v"(s1[2][3]));
            asm("v_cvt_pk_bf16_f32 %0, %1, %2" : "=v"(pk30) : "v"(s1[3][0]), "v"(s1[3][1]));
            asm("v_cvt_pk_bf16_f32 %0, %1, %2" : "=v"(pk31) : "v"(s1[3][2]), "v"(s1[3][3]));
            asm("v_permlane32_swap_b32 %0, %1" : "+v"(pk00), "+v"(pk10));
            asm("v_permlane32_swap_b32 %0, %1" : "+v"(pk01), "+v"(pk11));
            asm("v_permlane32_swap_b32 %0, %1" : "+v"(pk20), "+v"(pk30));
            asm("v_permlane32_swap_b32 %0, %1" : "+v"(pk21), "+v"(pk31));
            UW ua, ub;
            ua.w[0] = pk00; ua.w[1] = pk01; ua.w[2] = pk10; ua.w[3] = pk11;
            ub.w[0] = pk20; ub.w[1] = pk21; ub.w[2] = pk30; ub.w[3] = pk31;
            pa0s1 = ua.v; pa1s1 = ub.v;
        }

        // PV + ones-column, both sets share the V fragments
        __builtin_amdgcn_s_setprio(1);
#pragma unroll
        for (int dn = 0; dn < 4; ++dn) {
            bf16x8 vb0 = *(const bf16x8*)(Vc + (fragb0 + dn * 2048));
            bf16x8 vb1 = *(const bf16x8*)(Vc + (fragb1 + dn * 2048));
            o0[dn] = __builtin_amdgcn_mfma_f32_16x16x32_bf16(pa0s0, vb0, o0[dn], 0, 0, 0);
            o0[dn] = __builtin_amdgcn_mfma_f32_16x16x32_bf16(pa1s0, vb1, o0[dn], 0, 0, 0);
            o1[dn] = __builtin_amdgcn_mfma_f32_16x16x32_bf16(pa0s1, vb0, o1[dn], 0, 0, 0);
            o1[dn] = __builtin_amdgcn_mfma_f32_16x16x32_bf16(pa1s1, vb1, o1[dn], 0, 0, 0);
        }
        ol0 = __builtin_amdgcn_mfma_f32_16x16x32_bf16(pa0s0, ones, ol0, 0, 0, 0);
        ol0 = __builtin_amdgcn_mfma_f32_16x16x32_bf16(pa1s0, ones, ol0, 0, 0, 0);
        ol1 = __builtin_amdgcn_mfma_f32_16x16x32_bf16(pa0s1, ones, ol1, 0, 0, 0);
        ol1 = __builtin_amdgcn_mfma_f32_16x16x32_bf16(pa1s1, ones, ol1, 0, 0, 0);
        __builtin_amdgcn_s_setprio(0);

        if (more) {
            stK((char*)Kl[cur ^ 1], nk0, nk1);
            stV((char*)Vl[cur ^ 1], nv0, nv1);
        }
        __syncthreads();
        cur ^= 1;
    }

    // epilogue: normalize, write both sets
    float li0[4], li1[4];
#pragma unroll
    for (int j = 0; j < 4; ++j) { li0[j] = 1.0f / ol0[j]; li1[j] = 1.0f / ol1[j]; }
#pragma unroll
    for (int dn = 0; dn < 4; ++dn)
#pragma unroll
        for (int j = 0; j < 4; ++j) {
            const int row0 = b * SEQLEN + qb0 + lg * 4 + j;
            const int row1 = b * SEQLEN + qb1 + lg * 4 + j;
            const int col = h * 64 + dn * 16 + lr;
            attn_out[(size_t)row0 * EMB + col] = (bf16_t)(o0[dn][j] * li0[j]);
            attn_out[(size_t)row1 * EMB + col] = (bf16_t)(o1[dn][j] * li1[j]);
        }
}

// ---------------------------------------------------------------------------
extern "C" void kernel_launch(void* const* d_in, const int* in_sizes, int n_in,
                              void* d_out, int out_size, void* d_ws, size_t ws_size,
                              hipStream_t stream)
{
    const float* X     = (const float*)d_in[0];
    const float* W_qkv = (const float*)d_in[1];
    const float* b_qkv = (const float*)d_in[2];
    const float* W_out = (const float*)d_in[3];
    const float* b_out = (const float*)d_in[4];
    float* out = (float*)d_out;

    char* ws = (char*)d_ws;
    bf16_t* Wqkv_t = (bf16_t*)ws;                           //  6 MB [3072][1024]
    bf16_t* Wout_t = (bf16_t*)(ws + 6u * 1024 * 1024);      //  2 MB [1024][1024]
    bf16_t* qkv    = (bf16_t*)(ws + 8u * 1024 * 1024);      // 24 MB [4096][3072] (V region unused)
    bf16_t* attn   = (bf16_t*)(ws + 32u * 1024 * 1024);     //  8 MB [4096][1024]
    bf16_t* Xb     = (bf16_t*)(ws + 40u * 1024 * 1024);     //  8 MB [4096][1024]
    bf16_t* Vt_g   = (bf16_t*)(ws + 48u * 1024 * 1024);     //  8 MB [32][64][2048]

    dim3 blk(256);
    transpose_weights<<<dim3(64, 16), blk, 0, stream>>>(W_qkv, W_out, Wqkv_t, Wout_t);
    cvt_f32_bf16<<<4096 * 1024 / (256 * 8), blk, 0, stream>>>(X, Xb, 4096 * 1024);

    // qkv = Xb @ W_qkv + b_qkv; V col-blocks written transposed into Vt_g
    gemm_bt_kernel<true, true><<<(4096 / 128) * (N3 / 128), blk, 0, stream>>>(
        Xb, Wqkv_t, b_qkv, (void*)qkv, Vt_g, 1, 4096, N3, EMB);

    // causal flash attention (QBLK=128, 2 q-sets/wave) -> attn [4096][1024]
    attn_kernel<<<512, blk, 0, stream>>>(qkv, Vt_g, attn);

    // out = attn @ W_out + b_out  (fp32 out)
    gemm_bt_kernel<false, false><<<(4096 / 128) * (EMB / 128), blk, 0, stream>>>(
        attn, Wout_t, b_out, (void*)out, nullptr, 0, 4096, EMB, EMB);
}